// Round 3
// baseline (1215.318 us; speedup 1.0000x reference)
//
#include <hip/hip_runtime.h>

#define NT 8192      // tokens = B*S
#define DIM 1024     // D
#define FDIM 4096    // F
#define NEXP 8       // experts

typedef __attribute__((ext_vector_type(8))) short bfx8;   // 8 bf16 (4 VGPRs)
typedef __attribute__((ext_vector_type(4))) float fx4;    // MFMA accumulator

__device__ __forceinline__ unsigned short f2bf(float f) {
  union { float f; unsigned u; } v; v.f = f;
  unsigned u = v.u;
  unsigned r = u + 0x7FFFu + ((u >> 16) & 1u);   // round-to-nearest-even
  return (unsigned short)(r >> 16);
}

__device__ __forceinline__ void gload16(const void* g, void* l) {
  __builtin_amdgcn_global_load_lds(
      (const __attribute__((address_space(1))) unsigned int*)g,
      (__attribute__((address_space(3))) unsigned int*)l, 16, 0, 0);
}

// ---------------- zero counters ----------------
__global__ void k_zero(int* __restrict__ counts) {
  if (threadIdx.x < NEXP) counts[threadIdx.x] = 0;
}

// ---------------- routing: argmax affinity + alpha ----------------
__global__ __launch_bounds__(256) void k_routing(
    const float* __restrict__ x, const float* __restrict__ cent,
    int* __restrict__ eid, float* __restrict__ alpha, int* __restrict__ counts)
{
  const int t = blockIdx.x, tid = threadIdx.x;
  const float4 xv = ((const float4*)(x + (size_t)t * DIM))[tid];
  float acc[NEXP];
#pragma unroll
  for (int e = 0; e < NEXP; ++e) {
    const float4 cv = ((const float4*)(cent + (size_t)e * DIM))[tid];
    acc[e] = xv.x * cv.x + xv.y * cv.y + xv.z * cv.z + xv.w * cv.w;
  }
#pragma unroll
  for (int off = 32; off > 0; off >>= 1)
#pragma unroll
    for (int e = 0; e < NEXP; ++e) acc[e] += __shfl_down(acc[e], off);
  __shared__ float part[4][NEXP];
  const int lane = tid & 63, w = tid >> 6;
  if (lane == 0)
#pragma unroll
    for (int e = 0; e < NEXP; ++e) part[w][e] = acc[e];
  __syncthreads();
  if (tid == 0) {
    int best = 0; float bv = -1e30f;
#pragma unroll
    for (int e = 0; e < NEXP; ++e) {
      float v = part[0][e] + part[1][e] + part[2][e] + part[3][e];
      if (v > bv) { bv = v; best = e; }   // strict > keeps first max (matches argmax)
    }
    eid[t] = best;
    alpha[t] = 1.0f / (1.0f + expf(-bv));
    atomicAdd(&counts[best], 1);
  }
}

// ---------------- exclusive scan of 8 counts ----------------
__global__ void k_scan(const int* __restrict__ counts, int* __restrict__ bs, int* __restrict__ cur) {
  if (threadIdx.x == 0) {
    int s = 0;
    for (int e = 0; e < NEXP; ++e) { bs[e] = s; cur[e] = s; s += counts[e]; }
  }
}

// ---------------- LayerNorm + counting-sort scatter (bf16) ----------------
__global__ __launch_bounds__(256) void k_ln_scatter(
    const float* __restrict__ x, const float* __restrict__ g, const float* __restrict__ b,
    const int* __restrict__ eid, int* __restrict__ cur,
    int* __restrict__ row_tok, unsigned short* __restrict__ xln)
{
  const int t = blockIdx.x, tid = threadIdx.x;
  const float4 xv = ((const float4*)(x + (size_t)t * DIM))[tid];
  float s = xv.x + xv.y + xv.z + xv.w;
  float ss = xv.x * xv.x + xv.y * xv.y + xv.z * xv.z + xv.w * xv.w;
#pragma unroll
  for (int off = 32; off > 0; off >>= 1) { s += __shfl_down(s, off); ss += __shfl_down(ss, off); }
  __shared__ float ps[4], pss[4];
  __shared__ float smu, srstd;
  __shared__ int spos, se;
  const int lane = tid & 63, w = tid >> 6;
  if (lane == 0) { ps[w] = s; pss[w] = ss; }
  __syncthreads();
  if (tid == 0) {
    const float sum = ps[0] + ps[1] + ps[2] + ps[3];
    const float sq  = pss[0] + pss[1] + pss[2] + pss[3];
    const float mu = sum * (1.0f / DIM);
    const float var = sq * (1.0f / DIM) - mu * mu;
    smu = mu; srstd = rsqrtf(var + 1e-5f);
    const int e = eid[t]; se = e;
    const int pos = atomicAdd(&cur[e], 1);
    row_tok[pos] = t;
    spos = pos;
  }
  __syncthreads();
  const float mu = smu, rstd = srstd;
  const int e = se, pos = spos;
  const float4 gv = ((const float4*)(g + (size_t)e * DIM))[tid];
  const float4 bv = ((const float4*)(b + (size_t)e * DIM))[tid];
  ushort4 o;
  o.x = f2bf((xv.x - mu) * rstd * gv.x + bv.x);
  o.y = f2bf((xv.y - mu) * rstd * gv.y + bv.y);
  o.z = f2bf((xv.z - mu) * rstd * gv.z + bv.z);
  o.w = f2bf((xv.w - mu) * rstd * gv.w + bv.w);
  ((ushort4*)(xln + (size_t)pos * DIM))[tid] = o;
}

// ---------------- transpose fp32 [R][C] -> bf16 [C][R], 64x64 tiles ----------------
// bf16 conversion at LDS write; pitch 78 ushorts breaks the stride-544-dword
// bank degeneracy (read-phase row-lanes hit 4 banks instead of 1).
__global__ __launch_bounds__(256) void k_transpose(
    const float* __restrict__ in, unsigned short* __restrict__ outT, int R, int C)
{
  __shared__ unsigned short T[64 * 78];
  const int e = blockIdx.z;
  const float* src = in + (size_t)e * R * C;
  unsigned short* dst = outT + (size_t)e * R * C;
  const int r0 = blockIdx.y * 64, c0 = blockIdx.x * 64;
  const int t = threadIdx.x;
  const int ry = t >> 4, c4 = t & 15;
#pragma unroll
  for (int i = 0; i < 4; ++i) {
    const int r = ry + i * 16;
    const float4 v = *(const float4*)(src + (size_t)(r0 + r) * C + c0 + c4 * 4);
    const unsigned w0 = (unsigned)f2bf(v.x) | ((unsigned)f2bf(v.y) << 16);
    const unsigned w1 = (unsigned)f2bf(v.z) | ((unsigned)f2bf(v.w) << 16);
    *(unsigned*)&T[r * 78 + c4 * 4]     = w0;
    *(unsigned*)&T[r * 78 + c4 * 4 + 2] = w1;
  }
  __syncthreads();
  const int rb = t & 7, cy = t >> 3;
#pragma unroll
  for (int i = 0; i < 2; ++i) {
    const int c = cy + i * 32;
    unsigned short o[8];
#pragma unroll
    for (int u = 0; u < 8; ++u) o[u] = T[(rb * 8 + u) * 78 + c];
    *(uint4*)(dst + (size_t)(c0 + c) * R + r0 + rb * 8) = *(const uint4*)o;
  }
}

// ---------------- grouped MFMA GEMM, 128x128 tile, BK=32, 4 waves ----------------
// 2-phase double-buffered pipeline (T3-min): stage(next) issued before
// ds_read+MFMA(cur); drain via inline vmcnt(0) + raw s_barrier.
// Grid: x = m-block (fast) so concurrent blocks share one weight panel.
template<int K, int N, bool FIRST>
__global__ __launch_bounds__(256) void k_gemm(
    const unsigned short* __restrict__ A,
    const unsigned short* __restrict__ Bt,
    const float* __restrict__ bias,
    const int* __restrict__ bs, const int* __restrict__ counts,
    unsigned short* __restrict__ Hout,
    const int* __restrict__ row_tok, const float* __restrict__ alpha,
    const float* __restrict__ xin, float* __restrict__ out)
{
  const int e = blockIdx.z;
  const int cnt = counts[e];
  const int m0 = blockIdx.x * 128;     // m fast-varying
  if (m0 >= cnt) return;
  const int n0 = blockIdx.y * 128;
  const int rbase = bs[e];

  __shared__ unsigned short lA[2][128 * 32];   // linear (global_load_lds dest)
  __shared__ unsigned short lB[2][128 * 32];

  const int tid = threadIdx.x;
  const int lane = tid & 63, wv = tid >> 6;
  const int wm = (wv >> 1) * 64, wn = (wv & 1) * 64;
  const int lr = lane & 15, lg = lane >> 4;

  fx4 acc[4][4] = {};

  const unsigned short* Bte = Bt + (size_t)e * N * K;

  // staging geometry: chunk g = p*256+tid -> row g>>2, k-off (g&3)*8;
  // LDS linear elem offset 8*g = wave-uniform (p*4+wv)*512 + lane*8.
  const unsigned short* aP[2];
  const unsigned short* bP[2];
#pragma unroll
  for (int p = 0; p < 2; ++p) {
    const int g = p * 256 + tid;
    const int row = g >> 2, kq = (g & 3) * 8;
    int ar = rbase + m0 + row;
    ar = ar < NT ? ar : NT - 1;               // clamp: garbage rows masked at epilogue
    aP[p] = A + (size_t)ar * K + kq;
    bP[p] = Bte + (size_t)(n0 + row) * K + kq;
  }

#define STAGE(buf, k0)                                   \
  gload16(aP[0] + (k0), &lA[buf][(0 * 4 + wv) * 512]);   \
  gload16(aP[1] + (k0), &lA[buf][(1 * 4 + wv) * 512]);   \
  gload16(bP[0] + (k0), &lB[buf][(0 * 4 + wv) * 512]);   \
  gload16(bP[1] + (k0), &lB[buf][(1 * 4 + wv) * 512]);

  STAGE(0, 0)
  asm volatile("s_waitcnt vmcnt(0)" ::: "memory");
  __builtin_amdgcn_s_barrier();
  __builtin_amdgcn_sched_barrier(0);

  int cur = 0;
  for (int k0 = 0; k0 < K; k0 += 32) {
    if (k0 + 32 < K) { STAGE(cur ^ 1, k0 + 32) }
    bfx8 af[4], bf[4];
#pragma unroll
    for (int i = 0; i < 4; ++i)
      af[i] = *(const bfx8*)(&lA[cur][(wm + i * 16 + lr) * 32 + lg * 8]);
#pragma unroll
    for (int j = 0; j < 4; ++j)
      bf[j] = *(const bfx8*)(&lB[cur][(wn + j * 16 + lr) * 32 + lg * 8]);
#pragma unroll
    for (int i = 0; i < 4; ++i)
#pragma unroll
      for (int j = 0; j < 4; ++j)
        acc[i][j] = __builtin_amdgcn_mfma_f32_16x16x32_bf16(af[i], bf[j], acc[i][j], 0, 0, 0);
    asm volatile("s_waitcnt vmcnt(0)" ::: "memory");
    __builtin_amdgcn_s_barrier();
    __builtin_amdgcn_sched_barrier(0);
    cur ^= 1;
  }
#undef STAGE

  if constexpr (FIRST) {
#pragma unroll
    for (int i = 0; i < 4; ++i) {
#pragma unroll
      for (int r = 0; r < 4; ++r) {
        const int rl = wm + i * 16 + lg * 4 + r;
        if (m0 + rl >= cnt) continue;
        unsigned short* hrow = Hout + (size_t)(rbase + m0 + rl) * N;
#pragma unroll
        for (int j = 0; j < 4; ++j) {
          const int col = n0 + wn + j * 16 + lr;
          float v = acc[i][j][r] + bias[e * N + col];
          v = v > 0.f ? v : 0.f;
          hrow[col] = f2bf(v);
        }
      }
    }
  } else {
#pragma unroll
    for (int i = 0; i < 4; ++i) {
#pragma unroll
      for (int r = 0; r < 4; ++r) {
        const int rl = wm + i * 16 + lg * 4 + r;
        if (m0 + rl >= cnt) continue;
        const int tok = row_tok[rbase + m0 + rl];
        const float al = alpha[tok];
        const float* xrow = xin + (size_t)tok * N;
        float* orow = out + (size_t)tok * N;
#pragma unroll
        for (int j = 0; j < 4; ++j) {
          const int col = n0 + wn + j * 16 + lr;
          orow[col] = xrow[col] + al * (acc[i][j][r] + bias[e * N + col]);
        }
      }
    }
  }
}

extern "C" void kernel_launch(void* const* d_in, const int* in_sizes, int n_in,
                              void* d_out, int out_size, void* d_ws, size_t ws_size,
                              hipStream_t stream)
{
  const float* x    = (const float*)d_in[0];
  const float* cent = (const float*)d_in[1];
  const float* ln_g = (const float*)d_in[2];
  const float* ln_b = (const float*)d_in[3];
  const float* w1   = (const float*)d_in[4];
  const float* b1   = (const float*)d_in[5];
  const float* w2   = (const float*)d_in[6];
  const float* b2   = (const float*)d_in[7];
  float* out = (float*)d_out;

  char* ws = (char*)d_ws;
  unsigned short* xln  = (unsigned short*)(ws);                          // 16 MB [NT][DIM] bf16
  unsigned short* hbuf = (unsigned short*)(ws + (16ull << 20));          // 64 MB [NT][FDIM] bf16
  unsigned short* w1t  = (unsigned short*)(ws + (80ull << 20));          // 64 MB [E][F][D] bf16
  unsigned short* w2t  = (unsigned short*)(ws + (144ull << 20));         // 64 MB [E][D][F] bf16
  char* tail = ws + (208ull << 20);
  int*   eid    = (int*)(tail);
  float* alpha  = (float*)(tail + 32768);
  int*   rowtok = (int*)(tail + 65536);
  int*   counts = (int*)(tail + 98304);
  int*   basep  = counts + 16;
  int*   cur    = counts + 32;

  k_zero<<<1, 64, 0, stream>>>(counts);
  k_routing<<<NT, 256, 0, stream>>>(x, cent, eid, alpha, counts);
  k_scan<<<1, 1, 0, stream>>>(counts, basep, cur);
  k_ln_scatter<<<NT, 256, 0, stream>>>(x, ln_g, ln_b, eid, cur, rowtok, xln);
  k_transpose<<<dim3(FDIM / 64, DIM / 64, NEXP), 256, 0, stream>>>(w1, w1t, DIM, FDIM);
  k_transpose<<<dim3(DIM / 64, FDIM / 64, NEXP), 256, 0, stream>>>(w2, w2t, FDIM, DIM);
  k_gemm<DIM, FDIM, true><<<dim3(NT / 128, FDIM / 128, NEXP), 256, 0, stream>>>(
      xln, w1t, b1, basep, counts, hbuf, nullptr, nullptr, nullptr, nullptr);
  k_gemm<FDIM, DIM, false><<<dim3(NT / 128, DIM / 128, NEXP), 256, 0, stream>>>(
      hbuf, w2t, b2, basep, counts, nullptr, rowtok, alpha, x, out);
}

// Round 4
// 545.468 us; speedup vs baseline: 2.2280x; 2.2280x over previous
//
#include <hip/hip_runtime.h>

#define NT 8192      // tokens = B*S
#define DIM 1024     // D
#define FDIM 4096    // F
#define NEXP 8       // experts

typedef __attribute__((ext_vector_type(8))) short bfx8;   // 8 bf16 (4 VGPRs)
typedef __attribute__((ext_vector_type(4))) float fx4;    // MFMA accumulator

__device__ __forceinline__ unsigned short f2bf(float f) {
  union { float f; unsigned u; } v; v.f = f;
  unsigned u = v.u;
  unsigned r = u + 0x7FFFu + ((u >> 16) & 1u);   // round-to-nearest-even
  return (unsigned short)(r >> 16);
}

__device__ __forceinline__ void gload16(const void* g, void* l) {
  __builtin_amdgcn_global_load_lds(
      (const __attribute__((address_space(1))) unsigned int*)g,
      (__attribute__((address_space(3))) unsigned int*)l, 16, 0, 0);
}

// ---------------- zero counters ----------------
__global__ void k_zero(int* __restrict__ counts) {
  if (threadIdx.x < NEXP) counts[threadIdx.x] = 0;
}

// ---------------- routing: argmax affinity + alpha ----------------
__global__ __launch_bounds__(256) void k_routing(
    const float* __restrict__ x, const float* __restrict__ cent,
    int* __restrict__ eid, float* __restrict__ alpha, int* __restrict__ counts)
{
  const int t = blockIdx.x, tid = threadIdx.x;
  const float4 xv = ((const float4*)(x + (size_t)t * DIM))[tid];
  float acc[NEXP];
#pragma unroll
  for (int e = 0; e < NEXP; ++e) {
    const float4 cv = ((const float4*)(cent + (size_t)e * DIM))[tid];
    acc[e] = xv.x * cv.x + xv.y * cv.y + xv.z * cv.z + xv.w * cv.w;
  }
#pragma unroll
  for (int off = 32; off > 0; off >>= 1)
#pragma unroll
    for (int e = 0; e < NEXP; ++e) acc[e] += __shfl_down(acc[e], off);
  __shared__ float part[4][NEXP];
  const int lane = tid & 63, w = tid >> 6;
  if (lane == 0)
#pragma unroll
    for (int e = 0; e < NEXP; ++e) part[w][e] = acc[e];
  __syncthreads();
  if (tid == 0) {
    int best = 0; float bv = -1e30f;
#pragma unroll
    for (int e = 0; e < NEXP; ++e) {
      float v = part[0][e] + part[1][e] + part[2][e] + part[3][e];
      if (v > bv) { bv = v; best = e; }   // strict > keeps first max (matches argmax)
    }
    eid[t] = best;
    alpha[t] = 1.0f / (1.0f + expf(-bv));
    atomicAdd(&counts[best], 1);
  }
}

// ---------------- exclusive scan of 8 counts ----------------
__global__ void k_scan(const int* __restrict__ counts, int* __restrict__ bs, int* __restrict__ cur) {
  if (threadIdx.x == 0) {
    int s = 0;
    for (int e = 0; e < NEXP; ++e) { bs[e] = s; cur[e] = s; s += counts[e]; }
  }
}

// ---------------- LayerNorm + counting-sort scatter (bf16) ----------------
__global__ __launch_bounds__(256) void k_ln_scatter(
    const float* __restrict__ x, const float* __restrict__ g, const float* __restrict__ b,
    const int* __restrict__ eid, int* __restrict__ cur,
    int* __restrict__ row_tok, unsigned short* __restrict__ xln)
{
  const int t = blockIdx.x, tid = threadIdx.x;
  const float4 xv = ((const float4*)(x + (size_t)t * DIM))[tid];
  float s = xv.x + xv.y + xv.z + xv.w;
  float ss = xv.x * xv.x + xv.y * xv.y + xv.z * xv.z + xv.w * xv.w;
#pragma unroll
  for (int off = 32; off > 0; off >>= 1) { s += __shfl_down(s, off); ss += __shfl_down(ss, off); }
  __shared__ float ps[4], pss[4];
  __shared__ float smu, srstd;
  __shared__ int spos, se;
  const int lane = tid & 63, w = tid >> 6;
  if (lane == 0) { ps[w] = s; pss[w] = ss; }
  __syncthreads();
  if (tid == 0) {
    const float sum = ps[0] + ps[1] + ps[2] + ps[3];
    const float sq  = pss[0] + pss[1] + pss[2] + pss[3];
    const float mu = sum * (1.0f / DIM);
    const float var = sq * (1.0f / DIM) - mu * mu;
    smu = mu; srstd = rsqrtf(var + 1e-5f);
    const int e = eid[t]; se = e;
    const int pos = atomicAdd(&cur[e], 1);
    row_tok[pos] = t;
    spos = pos;
  }
  __syncthreads();
  const float mu = smu, rstd = srstd;
  const int e = se, pos = spos;
  const float4 gv = ((const float4*)(g + (size_t)e * DIM))[tid];
  const float4 bv = ((const float4*)(b + (size_t)e * DIM))[tid];
  ushort4 o;
  o.x = f2bf((xv.x - mu) * rstd * gv.x + bv.x);
  o.y = f2bf((xv.y - mu) * rstd * gv.y + bv.y);
  o.z = f2bf((xv.z - mu) * rstd * gv.z + bv.z);
  o.w = f2bf((xv.w - mu) * rstd * gv.w + bv.w);
  ((ushort4*)(xln + (size_t)pos * DIM))[tid] = o;
}

// ---------------- transpose fp32 [R][C] -> bf16 [C][R], 64x64 tiles ----------------
__global__ __launch_bounds__(256) void k_transpose(
    const float* __restrict__ in, unsigned short* __restrict__ outT, int R, int C)
{
  __shared__ unsigned short T[64 * 78];
  const int e = blockIdx.z;
  const float* src = in + (size_t)e * R * C;
  unsigned short* dst = outT + (size_t)e * R * C;
  const int r0 = blockIdx.y * 64, c0 = blockIdx.x * 64;
  const int t = threadIdx.x;
  const int ry = t >> 4, c4 = t & 15;
#pragma unroll
  for (int i = 0; i < 4; ++i) {
    const int r = ry + i * 16;
    const float4 v = *(const float4*)(src + (size_t)(r0 + r) * C + c0 + c4 * 4);
    const unsigned w0 = (unsigned)f2bf(v.x) | ((unsigned)f2bf(v.y) << 16);
    const unsigned w1 = (unsigned)f2bf(v.z) | ((unsigned)f2bf(v.w) << 16);
    *(unsigned*)&T[r * 78 + c4 * 4]     = w0;
    *(unsigned*)&T[r * 78 + c4 * 4 + 2] = w1;
  }
  __syncthreads();
  const int rb = t & 7, cy = t >> 3;
#pragma unroll
  for (int i = 0; i < 2; ++i) {
    const int c = cy + i * 32;
    unsigned short o[8];
#pragma unroll
    for (int u = 0; u < 8; ++u) o[u] = T[(rb * 8 + u) * 78 + c];
    *(uint4*)(dst + (size_t)(c0 + c) * R + r0 + rb * 8) = *(const uint4*)o;
  }
}

// ---------------- grouped MFMA GEMM, 128x128 tile, BK=32, 4 waves ----------------
// R2-proven single-buffer structure + bijective XCD-chunked swizzle:
// one expert per XCD (grid/NEXP blocks per expert, NEXP==8==XCDs), m-fastest
// within each n-panel so concurrent blocks share one 256KB weight panel in L2.
template<int K, int N, bool FIRST>
__global__ __launch_bounds__(256) void k_gemm(
    const unsigned short* __restrict__ A,
    const unsigned short* __restrict__ Bt,
    const float* __restrict__ bias,
    const int* __restrict__ bs, const int* __restrict__ counts,
    unsigned short* __restrict__ Hout,
    const int* __restrict__ row_tok, const float* __restrict__ alpha,
    const float* __restrict__ xin, float* __restrict__ out)
{
  // 1D grid = NEXP * (NT/128) * (N/128). Chunked XCD transform: xcd gets a
  // contiguous chunk == one expert (blocks-per-expert divisible by 8).
  const int MB = NT / 128, NB = N / 128;
  const int per_e = MB * NB;
  const int bid = blockIdx.x;
  const int sbid = (bid & 7) * (per_e) + (bid >> 3) % per_e
                 + ((bid >> 3) / per_e) * 0;   // grid = 8*per_e exactly
  const int e = sbid / per_e;
  const int r = sbid % per_e;
  const int m0 = (r % MB) * 128;               // m fastest
  const int n0 = (r / MB) * 128;

  const int cnt = counts[e];
  if (m0 >= cnt) return;
  const int rbase = bs[e];

  __shared__ unsigned short lA[128 * 32];   // linear (global_load_lds dest)
  __shared__ unsigned short lB[128 * 32];

  const int tid = threadIdx.x;
  const int lane = tid & 63, wv = tid >> 6;
  const int wm = (wv >> 1) * 64, wn = (wv & 1) * 64;
  const int lr = lane & 15, lg = lane >> 4;

  fx4 acc[4][4] = {};

  const unsigned short* Bte = Bt + (size_t)e * N * K;

  // staging geometry: chunk g = p*256+tid -> row g>>2, k-off (g&3)*8;
  // LDS linear elem offset 8*g = wave-uniform (p*4+wv)*512 + lane*8.
  const unsigned short* aP[2];
  const unsigned short* bP[2];
  unsigned short* lAd[2];
  unsigned short* lBd[2];
#pragma unroll
  for (int p = 0; p < 2; ++p) {
    const int g = p * 256 + tid;
    const int row = g >> 2, kq = (g & 3) * 8;
    int ar = rbase + m0 + row;
    ar = ar < NT ? ar : NT - 1;               // clamp: garbage rows masked at epilogue
    aP[p] = A + (size_t)ar * K + kq;
    bP[p] = Bte + (size_t)(n0 + row) * K + kq;
    lAd[p] = &lA[(p * 4 + wv) * 512];
    lBd[p] = &lB[(p * 4 + wv) * 512];
  }

  for (int k0 = 0; k0 < K; k0 += 32) {
    gload16(aP[0] + k0, lAd[0]);
    gload16(aP[1] + k0, lAd[1]);
    gload16(bP[0] + k0, lBd[0]);
    gload16(bP[1] + k0, lBd[1]);
    __syncthreads();                          // compiler-managed vmcnt drain
    bfx8 af[4], bf[4];
#pragma unroll
    for (int i = 0; i < 4; ++i)
      af[i] = *(const bfx8*)(&lA[(wm + i * 16 + lr) * 32 + lg * 8]);
#pragma unroll
    for (int j = 0; j < 4; ++j)
      bf[j] = *(const bfx8*)(&lB[(wn + j * 16 + lr) * 32 + lg * 8]);
#pragma unroll
    for (int i = 0; i < 4; ++i)
#pragma unroll
      for (int j = 0; j < 4; ++j)
        acc[i][j] = __builtin_amdgcn_mfma_f32_16x16x32_bf16(af[i], bf[j], acc[i][j], 0, 0, 0);
    __syncthreads();
  }

  if constexpr (FIRST) {
#pragma unroll
    for (int i = 0; i < 4; ++i) {
#pragma unroll
      for (int r2 = 0; r2 < 4; ++r2) {
        const int rl = wm + i * 16 + lg * 4 + r2;
        if (m0 + rl >= cnt) continue;
        unsigned short* hrow = Hout + (size_t)(rbase + m0 + rl) * N;
#pragma unroll
        for (int j = 0; j < 4; ++j) {
          const int col = n0 + wn + j * 16 + lr;
          float v = acc[i][j][r2] + bias[e * N + col];
          v = v > 0.f ? v : 0.f;
          hrow[col] = f2bf(v);
        }
      }
    }
  } else {
#pragma unroll
    for (int i = 0; i < 4; ++i) {
#pragma unroll
      for (int r2 = 0; r2 < 4; ++r2) {
        const int rl = wm + i * 16 + lg * 4 + r2;
        if (m0 + rl >= cnt) continue;
        const int tok = row_tok[rbase + m0 + rl];
        const float al = alpha[tok];
        const float* xrow = xin + (size_t)tok * N;
        float* orow = out + (size_t)tok * N;
#pragma unroll
        for (int j = 0; j < 4; ++j) {
          const int col = n0 + wn + j * 16 + lr;
          orow[col] = xrow[col] + al * (acc[i][j][r2] + bias[e * N + col]);
        }
      }
    }
  }
}

extern "C" void kernel_launch(void* const* d_in, const int* in_sizes, int n_in,
                              void* d_out, int out_size, void* d_ws, size_t ws_size,
                              hipStream_t stream)
{
  const float* x    = (const float*)d_in[0];
  const float* cent = (const float*)d_in[1];
  const float* ln_g = (const float*)d_in[2];
  const float* ln_b = (const float*)d_in[3];
  const float* w1   = (const float*)d_in[4];
  const float* b1   = (const float*)d_in[5];
  const float* w2   = (const float*)d_in[6];
  const float* b2   = (const float*)d_in[7];
  float* out = (float*)d_out;

  char* ws = (char*)d_ws;
  unsigned short* xln  = (unsigned short*)(ws);                          // 16 MB [NT][DIM] bf16
  unsigned short* hbuf = (unsigned short*)(ws + (16ull << 20));          // 64 MB [NT][FDIM] bf16
  unsigned short* w1t  = (unsigned short*)(ws + (80ull << 20));          // 64 MB [E][F][D] bf16
  unsigned short* w2t  = (unsigned short*)(ws + (144ull << 20));         // 64 MB [E][D][F] bf16
  char* tail = ws + (208ull << 20);
  int*   eid    = (int*)(tail);
  float* alpha  = (float*)(tail + 32768);
  int*   rowtok = (int*)(tail + 65536);
  int*   counts = (int*)(tail + 98304);
  int*   basep  = counts + 16;
  int*   cur    = counts + 32;

  k_zero<<<1, 64, 0, stream>>>(counts);
  k_routing<<<NT, 256, 0, stream>>>(x, cent, eid, alpha, counts);
  k_scan<<<1, 1, 0, stream>>>(counts, basep, cur);
  k_ln_scatter<<<NT, 256, 0, stream>>>(x, ln_g, ln_b, eid, cur, rowtok, xln);
  k_transpose<<<dim3(FDIM / 64, DIM / 64, NEXP), 256, 0, stream>>>(w1, w1t, DIM, FDIM);
  k_transpose<<<dim3(DIM / 64, FDIM / 64, NEXP), 256, 0, stream>>>(w2, w2t, FDIM, DIM);
  k_gemm<DIM, FDIM, true><<<NEXP * (NT / 128) * (FDIM / 128), 256, 0, stream>>>(
      xln, w1t, b1, basep, counts, hbuf, nullptr, nullptr, nullptr, nullptr);
  k_gemm<FDIM, DIM, false><<<NEXP * (NT / 128) * (DIM / 128), 256, 0, stream>>>(
      hbuf, w2t, b2, basep, counts, nullptr, rowtok, alpha, x, out);
}